// Round 12
// baseline (1425.489 us; speedup 1.0000x reference)
//
#include <hip/hip_runtime.h>
#include <hip/hip_bf16.h>

// Problem dims
#define PP 512
#define QQ 64
#define BB 16
#define EE 256
#define HH 256
#define OO 256

typedef _Float16 half2_t __attribute__((ext_vector_type(2)));
typedef _Float16 f16x8 __attribute__((ext_vector_type(8)));
typedef float f32x4 __attribute__((ext_vector_type(4)));

__device__ __forceinline__ float fast_tanh(float x) {
    x = fminf(fmaxf(x, -15.f), 15.f);
    float e = __expf(2.f * x);
    return (e - 1.f) * __frcp_rn(e + 1.f);
}
__device__ __forceinline__ float fast_sigmoid(float x) {
    x = fminf(fmaxf(x, -30.f), 30.f);
    return __frcp_rn(1.f + __expf(-x));
}
__device__ __forceinline__ f16x8 cvt8(const float* __restrict__ p) {
    float4 r0 = *(const float4*)(p);
    float4 r1 = *(const float4*)(p + 4);
    f16x8 t;
    t[0] = (_Float16)r0.x; t[1] = (_Float16)r0.y;
    t[2] = (_Float16)r0.z; t[3] = (_Float16)r0.w;
    t[4] = (_Float16)r1.x; t[5] = (_Float16)r1.y;
    t[6] = (_Float16)r1.z; t[7] = (_Float16)r1.w;
    return t;
}
__device__ __forceinline__ float fdot2f(half2_t a, half2_t b, float c) {
#if defined(__has_builtin)
#if __has_builtin(__builtin_amdgcn_fdot2)
    return __builtin_amdgcn_fdot2(a, b, c, false);
#else
    return (float)a[0] * (float)b[0] + (float)a[1] * (float)b[1] + c;
#endif
#else
    return (float)a[0] * (float)b[0] + (float)a[1] * (float)b[1] + c;
#endif
}

// LDS-only barrier: orders ds_write -> barrier -> ds_read WITHOUT the
// vmcnt(0)/expcnt(0) drain __syncthreads() emits.
__device__ __forceinline__ void block_sync_lds() {
    __builtin_amdgcn_sched_barrier(0);
    asm volatile("s_waitcnt lgkmcnt(0)" ::: "memory");
    __builtin_amdgcn_s_barrier();
    __builtin_amdgcn_sched_barrier(0);
}

// ---------------------------------------------------------------------------
// One-shot fp32->f16 pre-conversion into d_out scratch (d_out is only
// written by the FINAL gru kernel). f16-element layout in dst:
//   [0,      65536)   Wuq      (256x256)
//   [65536, 131072)   Wup      (256x256)
//   [131072,262144)   Wg2 = Wg rows [256,512)  (256x512)
//   [262144,458752)   w_ih     (768x256)
//   [458752,720896)   question (1024x256 = 262144 elems)
//   [720896,2818048)  passage  (8192x256 = 2097152 elems)
// Total 5.38 MiB < 8 MiB d_out.
// ROUND-11 BUG FIXED HERE: the previous layout gave question only 65536
// elements (the old gap), so rows >=256 of ques_h aliased pass_h ->
// absmax 0.19. Regions now sized to the actual tensors.
// ---------------------------------------------------------------------------
__global__ __launch_bounds__(256) void conv_k(
    const float* __restrict__ Wuq, const float* __restrict__ Wup,
    const float* __restrict__ Wg2, const float* __restrict__ w_ih,
    const float* __restrict__ question, const float* __restrict__ passage,
    _Float16* __restrict__ dst)
{
    const long i = ((long)blockIdx.x * 256 + threadIdx.x) * 8;
    const float* src;
    long off;
    if (i < 65536)       { src = Wuq;      off = i; }
    else if (i < 131072) { src = Wup;      off = i - 65536; }
    else if (i < 262144) { src = Wg2;      off = i - 131072; }
    else if (i < 458752) { src = w_ih;     off = i - 262144; }
    else if (i < 720896) { src = question; off = i - 458752; }
    else                 { src = passage;  off = i - 720896; }
    *(f16x8*)(dst + i) = cvt8(src + off);
}

// ---------------------------------------------------------------------------
// MFMA GEMM body, register-resident f16 B (pre-converted by conv_k).
// All A paths are f16. 4 waves, BM=64, wave w owns rows [bm*64+16w,+16).
// AMODE: 3 = A f16 (row stride KK)
//        2 = concat (KK=512): k<256 -> Ah2 (stride 256), k>=256 -> Ah
// EPI:   0 none | 1 +bias[n] | 2 sigmoid(acc)*gateC[m*256+n]
// Fragment mappings hardware-verified by the v6 GRU kernel.
// ---------------------------------------------------------------------------
template <int AMODE, int EPI, int BN, int KK>
__device__ __forceinline__ void gemm_body(
    const _Float16* __restrict__ Ah,
    const _Float16* __restrict__ Ah2,
    const _Float16* __restrict__ Bh,
    const float* __restrict__ bias,
    const _Float16* __restrict__ gateC,
    _Float16* __restrict__ Cout, int N, int bm, int bn, int tid)
{
    constexpr int NT = BN / 16;   // n-tiles per block (4 or 2)
    constexpr int KS = KK / 32;   // k-steps (8 or 16)
    const int w = tid >> 6;
    const int lane = tid & 63;
    const int ln = lane & 15;     // fragment n / m index
    const int lk = lane >> 4;     // fragment k-group

    f16x8 bf[NT][KS];
#pragma unroll
    for (int c = 0; c < NT; c++) {
        const _Float16* wp = Bh + (long)(bn * BN + c * 16 + ln) * KK + 8 * lk;
#pragma unroll
        for (int kk = 0; kk < KS; kk++)
            bf[c][kk] = *(const f16x8*)(wp + kk * 32);
    }

    const long arow = (long)bm * 64 + w * 16 + ln;
    f32x4 acc[NT];
#pragma unroll
    for (int c = 0; c < NT; c++) acc[c] = (f32x4){0.f, 0.f, 0.f, 0.f};

#pragma unroll
    for (int kk = 0; kk < KS; kk++) {
        f16x8 a;
        if (AMODE == 3) {
            a = *(const f16x8*)(Ah + arow * KK + kk * 32 + 8 * lk);
        } else {  // AMODE == 2
            if (kk < KS / 2)
                a = *(const f16x8*)(Ah2 + arow * 256 + kk * 32 + 8 * lk);
            else
                a = *(const f16x8*)(Ah + arow * 256 + (kk - KS / 2) * 32 + 8 * lk);
        }
#pragma unroll
        for (int c = 0; c < NT; c++)
            acc[c] = __builtin_amdgcn_mfma_f32_16x16x32_f16(a, bf[c][kk], acc[c], 0, 0, 0);
    }

#pragma unroll
    for (int c = 0; c < NT; c++) {
        const int n = bn * BN + c * 16 + ln;
        const float bi = (EPI == 1) ? bias[n] : 0.f;
#pragma unroll
        for (int i = 0; i < 4; i++) {
            const long m = (long)bm * 64 + w * 16 + lk * 4 + i;
            float v = acc[c][i];
            if (EPI == 1) v += bi;
            if (EPI == 2) v = fast_sigmoid(v) * (float)gateC[m * 256 + n];
            Cout[m * (long)N + n] = (_Float16)v;
        }
    }
}

template <int AMODE, int EPI, int BN, int KK>
__global__ __launch_bounds__(256)
__attribute__((amdgpu_waves_per_eu(2, 2)))
void gemm_mfma(
    const _Float16* __restrict__ Ah,
    const _Float16* __restrict__ Ah2,
    const _Float16* __restrict__ Bh,
    const float* __restrict__ bias,
    const _Float16* __restrict__ gateC,
    _Float16* __restrict__ Cout, int N)
{
    gemm_body<AMODE, EPI, BN, KK>(Ah, Ah2, Bh, bias, gateC, Cout, N,
                                  blockIdx.x, blockIdx.y, threadIdx.x);
}

// Steps 1+2 merged (both independent, both <3,0,64,256>): bm<16 -> Wq GEMM
// (question_h @ Wuq^T), else -> Wp GEMM (passage_h @ Wup^T).
__global__ __launch_bounds__(256)
__attribute__((amdgpu_waves_per_eu(2, 2)))
void gemm12_k(
    const _Float16* __restrict__ qh, const _Float16* __restrict__ ph,
    const _Float16* __restrict__ wuq, const _Float16* __restrict__ wup,
    _Float16* __restrict__ Wq, _Float16* __restrict__ Wp)
{
    if (blockIdx.x < 16)
        gemm_body<3, 0, 64, 256>(qh, nullptr, wuq, nullptr, nullptr, Wq, 256,
                                 blockIdx.x, blockIdx.y, threadIdx.x);
    else
        gemm_body<3, 0, 64, 256>(ph, nullptr, wup, nullptr, nullptr, Wp, 256,
                                 blockIdx.x - 16, blockIdx.y, threadIdx.x);
}

// ---------------------------------------------------------------------------
// Fused attention: per block = one (p,b) pair (m = p*16+b).
// PV reads pre-converted f16 question.
// ---------------------------------------------------------------------------
__global__ __launch_bounds__(256) void attn_k(
    const _Float16* __restrict__ qh,     // (Q*B, E) f16
    const float* __restrict__ vvec,      // (H,) fp32
    const _Float16* __restrict__ Wp,     // (P*B, H) f16
    const _Float16* __restrict__ Wq,     // (Q*B, H) f16
    _Float16* __restrict__ Cc)           // (P*B, E) f16 out
{
    __shared__ float sc[QQ];
    __shared__ float aw[QQ];
    const int tid = threadIdx.x;
    const int blk = blockIdx.x;   // m = p*16 + b
    const int b = blk & 15;
    const int wave = tid >> 6, lane = tid & 63;

    float wp0[4], vv[4];
#pragma unroll
    for (int j = 0; j < 4; j++) {
        wp0[j] = (float)Wp[(long)blk * 256 + lane + 64 * j];
        vv[j] = vvec[lane + 64 * j];
    }
#pragma unroll 2
    for (int qi = 0; qi < 16; qi++) {
        const int q = wave * 16 + qi;
        const _Float16* wqp = Wq + (long)(q * 16 + b) * 256;
        float s = 0.f;
#pragma unroll
        for (int j = 0; j < 4; j++) {
            float x = (float)wqp[lane + 64 * j] + wp0[j];
            s += fast_tanh(x) * vv[j];
        }
#pragma unroll
        for (int off = 32; off; off >>= 1) s += __shfl_xor(s, off, 64);
        if (lane == 0) sc[q] = s;
    }
    __syncthreads();
    if (tid < 64) {
        float s = sc[tid];
        float mx = s;
#pragma unroll
        for (int off = 32; off; off >>= 1) mx = fmaxf(mx, __shfl_xor(mx, off, 64));
        float e = __expf(s - mx);
        float sum = e;
#pragma unroll
        for (int off = 32; off; off >>= 1) sum += __shfl_xor(sum, off, 64);
        aw[tid] = e * __frcp_rn(sum);
    }
    __syncthreads();
    float acc = 0.f;
#pragma unroll 4
    for (int q = 0; q < QQ; q++) {
        acc = fmaf(aw[q], (float)qh[(long)(q * 16 + b) * 256 + tid], acc);
    }
    Cc[(long)blk * 256 + tid] = (_Float16)acc;
}

// ---------------------------------------------------------------------------
// GRU scan, v12: full-row per thread, 1 wave/SIMD. 16 blocks (one per
// batch), 256 threads (4 waves) with waves_per_eu(1,1) -> 512-reg budget.
// (Unchanged from round 11 -- its evaluation was masked by the conv_k
// layout bug. See round-11 rationale: no k-split, no partial exchange,
// gates fully in-register, ONE barrier per step; per-wave overhead halves.)
// ---------------------------------------------------------------------------
__global__ __launch_bounds__(256)
__attribute__((amdgpu_waves_per_eu(1, 1)))
void gru_k(
    const float* __restrict__ whh,    // (768,256) fp32
    const float* __restrict__ bhh,    // (768,) fp32
    const _Float16* __restrict__ gi,  // (P*B, 768) f16 (b_ih folded in)
    float* __restrict__ out)          // (P,B,O) fp32
{
    __shared__ __align__(16) _Float16 hbuf[2][256];   // h broadcast, dbuf
    const int e = threadIdx.x;    // 0..255: output element
    const int b = blockIdx.x;     // batch

    // Full weight rows e (r), e+256 (z), e+512 (n): 3 x 128 half2.
    half2_t wr[128], wz[128], wn[128];
    {
        const float* pr = whh + (long)e * 256;
        const float* pz = whh + (long)(e + 256) * 256;
        const float* pn = whh + (long)(e + 512) * 256;
#pragma unroll
        for (int j = 0; j < 64; j++) {
            float4 a = *(const float4*)(pr + 4 * j);
            float4 c = *(const float4*)(pz + 4 * j);
            float4 d = *(const float4*)(pn + 4 * j);
            half2_t t;
            t[0] = (_Float16)a.x; t[1] = (_Float16)a.y; wr[2 * j] = t;
            t[0] = (_Float16)a.z; t[1] = (_Float16)a.w; wr[2 * j + 1] = t;
            t[0] = (_Float16)c.x; t[1] = (_Float16)c.y; wz[2 * j] = t;
            t[0] = (_Float16)c.z; t[1] = (_Float16)c.w; wz[2 * j + 1] = t;
            t[0] = (_Float16)d.x; t[1] = (_Float16)d.y; wn[2 * j] = t;
            t[0] = (_Float16)d.z; t[1] = (_Float16)d.w; wn[2 * j + 1] = t;
        }
    }
    const float b_r = bhh[e];
    const float b_z = bhh[e + 256];
    const float b_n = bhh[e + 512];
    const _Float16* gip = gi + (long)b * 768 + e;
    float* outp = out + (long)b * 256 + e;
    float gr = (float)gip[0], gz = (float)gip[256], gn = (float)gip[512];
    hbuf[0][e] = (_Float16)0.f;
    float h = 0.f;
    __syncthreads();

    int cur = 0;
    for (int t = 0; t < PP; t++) {
        // Prefetch NEXT step's gi (consumed after ~1100 cyc of dots).
        // t=511 reads one row past gi -- inside the 16 MiB ws, unused.
        float gr2, gz2, gn2;
        {
            const _Float16* gq = gip + 16 * 768;
            gr2 = (float)gq[0]; gz2 = (float)gq[256]; gn2 = (float)gq[512];
        }
        // Full 256-wide dots; all lanes read the SAME h sequence
        // (same-address LDS broadcast, conflict-free).
        const uint4* hp4 = (const uint4*)hbuf[cur];
        float ar = 0.f, az = 0.f, an = 0.f;
#pragma unroll
        for (int j = 0; j < 32; j++) {
            uint4 hp = hp4[j];
            half2_t h0 = __builtin_bit_cast(half2_t, hp.x);
            half2_t h1 = __builtin_bit_cast(half2_t, hp.y);
            half2_t h2 = __builtin_bit_cast(half2_t, hp.z);
            half2_t h3 = __builtin_bit_cast(half2_t, hp.w);
            ar = fdot2f(wr[4 * j + 0], h0, ar);
            ar = fdot2f(wr[4 * j + 1], h1, ar);
            ar = fdot2f(wr[4 * j + 2], h2, ar);
            ar = fdot2f(wr[4 * j + 3], h3, ar);
            az = fdot2f(wz[4 * j + 0], h0, az);
            az = fdot2f(wz[4 * j + 1], h1, az);
            az = fdot2f(wz[4 * j + 2], h2, az);
            az = fdot2f(wz[4 * j + 3], h3, az);
            an = fdot2f(wn[4 * j + 0], h0, an);
            an = fdot2f(wn[4 * j + 1], h1, an);
            an = fdot2f(wn[4 * j + 2], h2, an);
            an = fdot2f(wn[4 * j + 3], h3, an);
        }
        // Gates fully in-register (thread owns e end-to-end).
        float r = fast_sigmoid(gr + ar + b_r);
        float z = fast_sigmoid(gz + az + b_z);
        float n = fast_tanh(fmaf(r, an + b_n, gn));
        h = (1.f - z) * n + z * h;
        *outp = h;
        hbuf[cur ^ 1][e] = (_Float16)h;
        gr = gr2; gz = gz2; gn = gn2;
        gip += 16 * 768;
        outp += 16 * 256;
        block_sync_lds();
        cur ^= 1;
    }
}

// ---------------------------------------------------------------------------
extern "C" void kernel_launch(void* const* d_in, const int* in_sizes, int n_in,
                              void* d_out, int out_size, void* d_ws, size_t ws_size,
                              hipStream_t stream)
{
    const float* passage  = (const float*)d_in[0];   // (512,16,256) fp32
    const float* question = (const float*)d_in[1];   // (64,16,256) fp32
    const float* Wuq      = (const float*)d_in[2];   // (256,256) fp32
    const float* Wup      = (const float*)d_in[3];   // (256,256) fp32
    const float* vvec     = (const float*)d_in[4];   // (1,256) fp32
    const float* Wg       = (const float*)d_in[5];   // (512,512) fp32
    const float* w_ih     = (const float*)d_in[6];   // (768,256) fp32
    const float* w_hh     = (const float*)d_in[7];   // (768,256) fp32
    const float* b_ih     = (const float*)d_in[8];   // (768,) fp32
    const float* b_hh     = (const float*)d_in[9];   // (768,) fp32

    // Workspace layout (all fp16) — total footprint exactly 16 MiB.
    //   [0,      12.0MiB) : gi (8192x768)  — written LAST; overlaps Wq/Wp/c.
    //       [0,     0.5MiB) : Wq (1024x256)   dead after attn
    //       [0.5,   4.5MiB) : Wp (8192x256)   dead after attn
    //       [4.5,   8.5MiB) : c  (8192x256)   dead after gate GEMM
    //   [12MiB, 16MiB)     : cg (8192x256)    alive until gi GEMM done
    // d_out (8 MiB fp32 out) doubles as f16 scratch for pre-converted
    // weights + question + passage until gru_k (the only writer of out).
    char* ws = (char*)d_ws;
    _Float16* gi_ws = (_Float16*)(ws);
    _Float16* Wq_ws = (_Float16*)(ws);
    _Float16* Wp_ws = (_Float16*)(ws + (512u << 10));
    _Float16* c_ws  = (_Float16*)(ws + (4608u << 10));
    _Float16* cg_ws = (_Float16*)(ws + (12288u << 10));

    _Float16* wh     = (_Float16*)d_out;      // f16 scratch
    _Float16* wuq_h  = wh;                    // 256x256
    _Float16* wup_h  = wh + 65536;            // 256x256
    _Float16* wg2_h  = wh + 131072;           // 256x512
    _Float16* wih_h  = wh + 262144;           // 768x256
    _Float16* ques_h = wh + 458752;           // 1024x256 (262144 elems)
    _Float16* pass_h = wh + 720896;           // 8192x256 (2097152 elems)

    // 0) one-shot fp32->f16 conversion into d_out scratch
    //    total 2,818,048 f16 elems / (256 thr * 8) = 1376 blocks exactly
    conv_k<<<1376, 256, 0, stream>>>(Wuq, Wup, Wg + 256 * 512, w_ih,
                                     question, passage, wh);
    // 1+2) Wq = question @ Wuq^T (1024x256) and Wp = passage @ Wup^T
    //      (8192x256), merged into one dispatch
    gemm12_k<<<dim3(144, 4), 256, 0, stream>>>(ques_h, pass_h, wuq_h, wup_h,
                                               Wq_ws, Wp_ws);
    // 3) attention -> c (8192 x 256)
    attn_k<<<8192, 256, 0, stream>>>(ques_h, vvec, Wp_ws, Wq_ws, c_ws);
    // 4) cg = sigmoid([passage,c] @ Wg[256:512]^T) * c   (8192 x 256, K=512)
    gemm_mfma<2, 2, 32, 512><<<dim3(128, 8), 256, 0, stream>>>(
        c_ws, pass_h, wg2_h, nullptr, c_ws, cg_ws, 256);
    // 5) gi = cg @ w_ih^T + b_ih   (8192 x 768, K=256)
    gemm_mfma<3, 1, 64, 256><<<dim3(128, 12), 256, 0, stream>>>(
        cg_ws, nullptr, wih_h, b_ih, nullptr, gi_ws, 768);
    // 6) GRU scan -> out (fp32; overwrites the scratch)
    gru_k<<<16, 256, 0, stream>>>(w_hh, b_hh, gi_ws, (float*)d_out);
}

// Round 13
// 834.895 us; speedup vs baseline: 1.7074x; 1.7074x over previous
//
#include <hip/hip_runtime.h>
#include <hip/hip_bf16.h>

// Problem dims
#define PP 512
#define QQ 64
#define BB 16
#define EE 256
#define HH 256
#define OO 256

typedef _Float16 half2_t __attribute__((ext_vector_type(2)));
typedef _Float16 f16x8 __attribute__((ext_vector_type(8)));
typedef float f32x4 __attribute__((ext_vector_type(4)));

__device__ __forceinline__ float fast_tanh(float x) {
    x = fminf(fmaxf(x, -15.f), 15.f);
    float e = __expf(2.f * x);
    return (e - 1.f) * __frcp_rn(e + 1.f);
}
__device__ __forceinline__ float fast_sigmoid(float x) {
    x = fminf(fmaxf(x, -30.f), 30.f);
    return __frcp_rn(1.f + __expf(-x));
}
__device__ __forceinline__ f16x8 cvt8(const float* __restrict__ p) {
    float4 r0 = *(const float4*)(p);
    float4 r1 = *(const float4*)(p + 4);
    f16x8 t;
    t[0] = (_Float16)r0.x; t[1] = (_Float16)r0.y;
    t[2] = (_Float16)r0.z; t[3] = (_Float16)r0.w;
    t[4] = (_Float16)r1.x; t[5] = (_Float16)r1.y;
    t[6] = (_Float16)r1.z; t[7] = (_Float16)r1.w;
    return t;
}
__device__ __forceinline__ float fdot2f(half2_t a, half2_t b, float c) {
#if defined(__has_builtin)
#if __has_builtin(__builtin_amdgcn_fdot2)
    return __builtin_amdgcn_fdot2(a, b, c, false);
#else
    return (float)a[0] * (float)b[0] + (float)a[1] * (float)b[1] + c;
#endif
#else
    return (float)a[0] * (float)b[0] + (float)a[1] * (float)b[1] + c;
#endif
}

// LDS-only barrier: orders ds_write -> barrier -> ds_read WITHOUT the
// vmcnt(0)/expcnt(0) drain __syncthreads() emits.
__device__ __forceinline__ void block_sync_lds() {
    __builtin_amdgcn_sched_barrier(0);
    asm volatile("s_waitcnt lgkmcnt(0)" ::: "memory");
    __builtin_amdgcn_s_barrier();
    __builtin_amdgcn_sched_barrier(0);
}

// ---------------------------------------------------------------------------
// One-shot fp32->f16 pre-conversion into d_out scratch (d_out is only
// written by the FINAL gru kernel). f16-element layout in dst:
//   [0,      65536)   Wuq      (256x256)
//   [65536, 131072)   Wup      (256x256)
//   [131072,262144)   Wg2 = Wg rows [256,512)  (256x512)
//   [262144,458752)   w_ih     (768x256)
//   [458752,720896)   question (1024x256 = 262144 elems)
//   [720896,2818048)  passage  (8192x256 = 2097152 elems)
// Total 5.38 MiB < 8 MiB d_out.
// ---------------------------------------------------------------------------
__global__ __launch_bounds__(256) void conv_k(
    const float* __restrict__ Wuq, const float* __restrict__ Wup,
    const float* __restrict__ Wg2, const float* __restrict__ w_ih,
    const float* __restrict__ question, const float* __restrict__ passage,
    _Float16* __restrict__ dst)
{
    const long i = ((long)blockIdx.x * 256 + threadIdx.x) * 8;
    const float* src;
    long off;
    if (i < 65536)       { src = Wuq;      off = i; }
    else if (i < 131072) { src = Wup;      off = i - 65536; }
    else if (i < 262144) { src = Wg2;      off = i - 131072; }
    else if (i < 458752) { src = w_ih;     off = i - 262144; }
    else if (i < 720896) { src = question; off = i - 458752; }
    else                 { src = passage;  off = i - 720896; }
    *(f16x8*)(dst + i) = cvt8(src + off);
}

// ---------------------------------------------------------------------------
// MFMA GEMM body, register-resident f16 B (pre-converted by conv_k).
// All A paths are f16. 4 waves, BM=64, wave w owns rows [bm*64+16w,+16).
// AMODE: 3 = A f16 (row stride KK)
//        2 = concat (KK=512): k<256 -> Ah2 (stride 256), k>=256 -> Ah
// EPI:   0 none | 1 +bias[n] | 2 sigmoid(acc)*gateC[m*256+n]
// Fragment mappings hardware-verified by the v6 GRU kernel.
// ---------------------------------------------------------------------------
template <int AMODE, int EPI, int BN, int KK>
__device__ __forceinline__ void gemm_body(
    const _Float16* __restrict__ Ah,
    const _Float16* __restrict__ Ah2,
    const _Float16* __restrict__ Bh,
    const float* __restrict__ bias,
    const _Float16* __restrict__ gateC,
    _Float16* __restrict__ Cout, int N, int bm, int bn, int tid)
{
    constexpr int NT = BN / 16;   // n-tiles per block (4 or 2)
    constexpr int KS = KK / 32;   // k-steps (8 or 16)
    const int w = tid >> 6;
    const int lane = tid & 63;
    const int ln = lane & 15;     // fragment n / m index
    const int lk = lane >> 4;     // fragment k-group

    f16x8 bf[NT][KS];
#pragma unroll
    for (int c = 0; c < NT; c++) {
        const _Float16* wp = Bh + (long)(bn * BN + c * 16 + ln) * KK + 8 * lk;
#pragma unroll
        for (int kk = 0; kk < KS; kk++)
            bf[c][kk] = *(const f16x8*)(wp + kk * 32);
    }

    const long arow = (long)bm * 64 + w * 16 + ln;
    f32x4 acc[NT];
#pragma unroll
    for (int c = 0; c < NT; c++) acc[c] = (f32x4){0.f, 0.f, 0.f, 0.f};

#pragma unroll
    for (int kk = 0; kk < KS; kk++) {
        f16x8 a;
        if (AMODE == 3) {
            a = *(const f16x8*)(Ah + arow * KK + kk * 32 + 8 * lk);
        } else {  // AMODE == 2
            if (kk < KS / 2)
                a = *(const f16x8*)(Ah2 + arow * 256 + kk * 32 + 8 * lk);
            else
                a = *(const f16x8*)(Ah + arow * 256 + (kk - KS / 2) * 32 + 8 * lk);
        }
#pragma unroll
        for (int c = 0; c < NT; c++)
            acc[c] = __builtin_amdgcn_mfma_f32_16x16x32_f16(a, bf[c][kk], acc[c], 0, 0, 0);
    }

#pragma unroll
    for (int c = 0; c < NT; c++) {
        const int n = bn * BN + c * 16 + ln;
        const float bi = (EPI == 1) ? bias[n] : 0.f;
#pragma unroll
        for (int i = 0; i < 4; i++) {
            const long m = (long)bm * 64 + w * 16 + lk * 4 + i;
            float v = acc[c][i];
            if (EPI == 1) v += bi;
            if (EPI == 2) v = fast_sigmoid(v) * (float)gateC[m * 256 + n];
            Cout[m * (long)N + n] = (_Float16)v;
        }
    }
}

template <int AMODE, int EPI, int BN, int KK>
__global__ __launch_bounds__(256)
__attribute__((amdgpu_waves_per_eu(2, 2)))
void gemm_mfma(
    const _Float16* __restrict__ Ah,
    const _Float16* __restrict__ Ah2,
    const _Float16* __restrict__ Bh,
    const float* __restrict__ bias,
    const _Float16* __restrict__ gateC,
    _Float16* __restrict__ Cout, int N)
{
    gemm_body<AMODE, EPI, BN, KK>(Ah, Ah2, Bh, bias, gateC, Cout, N,
                                  blockIdx.x, blockIdx.y, threadIdx.x);
}

// Steps 1+2 merged (both independent, both <3,0,64,256>): bm<16 -> Wq GEMM
// (question_h @ Wuq^T), else -> Wp GEMM (passage_h @ Wup^T).
__global__ __launch_bounds__(256)
__attribute__((amdgpu_waves_per_eu(2, 2)))
void gemm12_k(
    const _Float16* __restrict__ qh, const _Float16* __restrict__ ph,
    const _Float16* __restrict__ wuq, const _Float16* __restrict__ wup,
    _Float16* __restrict__ Wq, _Float16* __restrict__ Wp)
{
    if (blockIdx.x < 16)
        gemm_body<3, 0, 64, 256>(qh, nullptr, wuq, nullptr, nullptr, Wq, 256,
                                 blockIdx.x, blockIdx.y, threadIdx.x);
    else
        gemm_body<3, 0, 64, 256>(ph, nullptr, wup, nullptr, nullptr, Wp, 256,
                                 blockIdx.x - 16, blockIdx.y, threadIdx.x);
}

// ---------------------------------------------------------------------------
// Fused attention: per block = one (p,b) pair (m = p*16+b).
// PV reads pre-converted f16 question.
// ---------------------------------------------------------------------------
__global__ __launch_bounds__(256) void attn_k(
    const _Float16* __restrict__ qh,     // (Q*B, E) f16
    const float* __restrict__ vvec,      // (H,) fp32
    const _Float16* __restrict__ Wp,     // (P*B, H) f16
    const _Float16* __restrict__ Wq,     // (Q*B, H) f16
    _Float16* __restrict__ Cc)           // (P*B, E) f16 out
{
    __shared__ float sc[QQ];
    __shared__ float aw[QQ];
    const int tid = threadIdx.x;
    const int blk = blockIdx.x;   // m = p*16 + b
    const int b = blk & 15;
    const int wave = tid >> 6, lane = tid & 63;

    float wp0[4], vv[4];
#pragma unroll
    for (int j = 0; j < 4; j++) {
        wp0[j] = (float)Wp[(long)blk * 256 + lane + 64 * j];
        vv[j] = vvec[lane + 64 * j];
    }
#pragma unroll 2
    for (int qi = 0; qi < 16; qi++) {
        const int q = wave * 16 + qi;
        const _Float16* wqp = Wq + (long)(q * 16 + b) * 256;
        float s = 0.f;
#pragma unroll
        for (int j = 0; j < 4; j++) {
            float x = (float)wqp[lane + 64 * j] + wp0[j];
            s += fast_tanh(x) * vv[j];
        }
#pragma unroll
        for (int off = 32; off; off >>= 1) s += __shfl_xor(s, off, 64);
        if (lane == 0) sc[q] = s;
    }
    __syncthreads();
    if (tid < 64) {
        float s = sc[tid];
        float mx = s;
#pragma unroll
        for (int off = 32; off; off >>= 1) mx = fmaxf(mx, __shfl_xor(mx, off, 64));
        float e = __expf(s - mx);
        float sum = e;
#pragma unroll
        for (int off = 32; off; off >>= 1) sum += __shfl_xor(sum, off, 64);
        aw[tid] = e * __frcp_rn(sum);
    }
    __syncthreads();
    float acc = 0.f;
#pragma unroll 4
    for (int q = 0; q < QQ; q++) {
        acc = fmaf(aw[q], (float)qh[(long)(q * 16 + b) * 256 + tid], acc);
    }
    Cc[(long)blk * 256 + tid] = (_Float16)acc;
}

// ---------------------------------------------------------------------------
// GRU scan, v10 (RESTORED -- best measured: 601us, twice). 16 blocks,
// 512 threads (8 waves, 2/SIMD via waves_per_eu(2,2) -> 256 unified regs).
//
// Full design-space record (rounds 0-12): dot2 half-split @2w/SIMD = 601
// (this kernel); MFMA = 622; hybrid dot2+MFMA = 771 (same-wave pipe mixing
// serializes); 1-wave/SIMD full-row = 1186 (no latency hiding, worse tax);
// single-barrier fused epilogue = 860; vmcnt-free barriers = neutral.
// Structural floor: VALU issue 768 cyc/SIMD + >=1/3 AGPR tax (384KB f16
// weights vs 256KB arch grant/CU) + LDS broadcast/barrier skeleton
// ~= 2800 cyc/step. Scan parallelism capped at 16 CUs by B=16 recurrence.
// ---------------------------------------------------------------------------
__global__ __launch_bounds__(512)
__attribute__((amdgpu_waves_per_eu(2, 2), amdgpu_num_vgpr(256)))
void gru_k(
    const float* __restrict__ whh,    // (768,256) fp32
    const float* __restrict__ bhh,    // (768,) fp32
    const _Float16* __restrict__ gi,  // (P*B, 768) f16 (b_ih folded in)
    float* __restrict__ out)          // (P,B,O) fp32
{
    __shared__ __align__(16) _Float16 hbuf[2][256];   // h broadcast, dbuf
    __shared__ float part[3][256];                    // q=1 partials
    const int tid = threadIdx.x;
    const int q = tid >> 8;       // K-half 0/1
    const int e = tid & 255;
    const int b = blockIdx.x;
    const int koff = q * 128;

    // Weight slices: rows e (r), e+256 (z), e+512 (n), cols [koff, koff+128)
    half2_t wr[64], wz[64], wn[64];
    {
        const float* pr = whh + (long)e * 256 + koff;
        const float* pz = whh + (long)(e + 256) * 256 + koff;
        const float* pn = whh + (long)(e + 512) * 256 + koff;
#pragma unroll
        for (int j = 0; j < 32; j++) {
            float4 a = *(const float4*)(pr + 4 * j);
            float4 c = *(const float4*)(pz + 4 * j);
            float4 d = *(const float4*)(pn + 4 * j);
            half2_t t;
            t[0] = (_Float16)a.x; t[1] = (_Float16)a.y; wr[2 * j] = t;
            t[0] = (_Float16)a.z; t[1] = (_Float16)a.w; wr[2 * j + 1] = t;
            t[0] = (_Float16)c.x; t[1] = (_Float16)c.y; wz[2 * j] = t;
            t[0] = (_Float16)c.z; t[1] = (_Float16)c.w; wz[2 * j + 1] = t;
            t[0] = (_Float16)d.x; t[1] = (_Float16)d.y; wn[2 * j] = t;
            t[0] = (_Float16)d.z; t[1] = (_Float16)d.w; wn[2 * j + 1] = t;
        }
    }
    float b_r = 0.f, b_z = 0.f, b_n = 0.f;
    _Float16 gr = (_Float16)0.f, gz = (_Float16)0.f, gn = (_Float16)0.f;
    const _Float16* gip = gi;
    float* outp = out;
    if (q == 0) {
        b_r = bhh[e];
        b_z = bhh[e + 256];
        b_n = bhh[e + 512];
        hbuf[0][e] = (_Float16)0.f;
        gip = gi + (long)b * 768 + e;
        gr = gip[0]; gz = gip[256]; gn = gip[512];   // step-0 gi
        outp = out + (long)b * 256 + e;
    }
    float h = 0.f;
    __syncthreads();

    int cur = 0;
    for (int t = 0; t < PP; t++) {
        // Prefetch NEXT step's gi. t=511 reads one row past gi -- inside
        // the 16 MiB workspace, value unused.
        _Float16 gr2 = (_Float16)0.f, gz2 = (_Float16)0.f, gn2 = (_Float16)0.f;
        if (q == 0) {
            const _Float16* gq = gip + 16 * 768;
            gr2 = gq[0]; gz2 = gq[256]; gn2 = gq[512];
        }
        // Half-dot over this thread's 128-wide k-slice of the broadcast h.
        const uint4* hp4 = ((const uint4*)hbuf[cur]) + q * 16;
        float ar = 0.f, az = 0.f, an = 0.f;
#pragma unroll
        for (int j = 0; j < 16; j++) {
            uint4 hp = hp4[j];
            half2_t h0 = __builtin_bit_cast(half2_t, hp.x);
            half2_t h1 = __builtin_bit_cast(half2_t, hp.y);
            half2_t h2 = __builtin_bit_cast(half2_t, hp.z);
            half2_t h3 = __builtin_bit_cast(half2_t, hp.w);
            ar = fdot2f(wr[4 * j + 0], h0, ar);
            ar = fdot2f(wr[4 * j + 1], h1, ar);
            ar = fdot2f(wr[4 * j + 2], h2, ar);
            ar = fdot2f(wr[4 * j + 3], h3, ar);
            az = fdot2f(wz[4 * j + 0], h0, az);
            az = fdot2f(wz[4 * j + 1], h1, az);
            az = fdot2f(wz[4 * j + 2], h2, az);
            az = fdot2f(wz[4 * j + 3], h3, az);
            an = fdot2f(wn[4 * j + 0], h0, an);
            an = fdot2f(wn[4 * j + 1], h1, an);
            an = fdot2f(wn[4 * j + 2], h2, an);
            an = fdot2f(wn[4 * j + 3], h3, an);
        }
        if (q) {
            part[0][e] = ar;
            part[1][e] = az;
            part[2][e] = an;
        }
        block_sync_lds();
        if (q == 0) {
            float ghr = ar + part[0][e] + b_r;
            float ghz = az + part[1][e] + b_z;
            float ghn = an + part[2][e] + b_n;
            float r = fast_sigmoid((float)gr + ghr);
            float z = fast_sigmoid((float)gz + ghz);
            float n = fast_tanh(fmaf(r, ghn, (float)gn));
            h = (1.f - z) * n + z * h;
            *outp = h;
            hbuf[cur ^ 1][e] = (_Float16)h;
            gr = gr2; gz = gz2; gn = gn2;
            gip += 16 * 768;
            outp += 16 * 256;
        }
        block_sync_lds();
        cur ^= 1;
    }
}

// ---------------------------------------------------------------------------
extern "C" void kernel_launch(void* const* d_in, const int* in_sizes, int n_in,
                              void* d_out, int out_size, void* d_ws, size_t ws_size,
                              hipStream_t stream)
{
    const float* passage  = (const float*)d_in[0];   // (512,16,256) fp32
    const float* question = (const float*)d_in[1];   // (64,16,256) fp32
    const float* Wuq      = (const float*)d_in[2];   // (256,256) fp32
    const float* Wup      = (const float*)d_in[3];   // (256,256) fp32
    const float* vvec     = (const float*)d_in[4];   // (1,256) fp32
    const float* Wg       = (const float*)d_in[5];   // (512,512) fp32
    const float* w_ih     = (const float*)d_in[6];   // (768,256) fp32
    const float* w_hh     = (const float*)d_in[7];   // (768,256) fp32
    const float* b_ih     = (const float*)d_in[8];   // (768,) fp32
    const float* b_hh     = (const float*)d_in[9];   // (768,) fp32

    // Workspace layout (all fp16) — total footprint exactly 16 MiB.
    //   [0,      12.0MiB) : gi (8192x768)  — written LAST; overlaps Wq/Wp/c.
    //       [0,     0.5MiB) : Wq (1024x256)   dead after attn
    //       [0.5,   4.5MiB) : Wp (8192x256)   dead after attn
    //       [4.5,   8.5MiB) : c  (8192x256)   dead after gate GEMM
    //   [12MiB, 16MiB)     : cg (8192x256)    alive until gi GEMM done
    // d_out (8 MiB fp32 out) doubles as f16 scratch for pre-converted
    // weights + question + passage until gru_k (the only writer of out).
    char* ws = (char*)d_ws;
    _Float16* gi_ws = (_Float16*)(ws);
    _Float16* Wq_ws = (_Float16*)(ws);
    _Float16* Wp_ws = (_Float16*)(ws + (512u << 10));
    _Float16* c_ws  = (_Float16*)(ws + (4608u << 10));
    _Float16* cg_ws = (_Float16*)(ws + (12288u << 10));

    _Float16* wh     = (_Float16*)d_out;      // f16 scratch
    _Float16* wuq_h  = wh;                    // 256x256
    _Float16* wup_h  = wh + 65536;            // 256x256
    _Float16* wg2_h  = wh + 131072;           // 256x512
    _Float16* wih_h  = wh + 262144;           // 768x256
    _Float16* ques_h = wh + 458752;           // 1024x256 (262144 elems)
    _Float16* pass_h = wh + 720896;           // 8192x256 (2097152 elems)

    // 0) one-shot fp32->f16 conversion into d_out scratch
    //    total 2,818,048 f16 elems / (256 thr * 8) = 1376 blocks exactly
    conv_k<<<1376, 256, 0, stream>>>(Wuq, Wup, Wg + 256 * 512, w_ih,
                                     question, passage, wh);
    // 1+2) Wq = question @ Wuq^T (1024x256) and Wp = passage @ Wup^T
    //      (8192x256), merged into one dispatch
    gemm12_k<<<dim3(144, 4), 256, 0, stream>>>(ques_h, pass_h, wuq_h, wup_h,
                                               Wq_ws, Wp_ws);
    // 3) attention -> c (8192 x 256)
    attn_k<<<8192, 256, 0, stream>>>(ques_h, vvec, Wp_ws, Wq_ws, c_ws);
    // 4) cg = sigmoid([passage,c] @ Wg[256:512]^T) * c   (8192 x 256, K=512)
    gemm_mfma<2, 2, 32, 512><<<dim3(128, 8), 256, 0, stream>>>(
        c_ws, pass_h, wg2_h, nullptr, c_ws, cg_ws, 256);
    // 5) gi = cg @ w_ih^T + b_ih   (8192 x 768, K=256)
    gemm_mfma<3, 1, 64, 256><<<dim3(128, 12), 256, 0, stream>>>(
        cg_ws, nullptr, wih_h, b_ih, nullptr, gi_ws, 768);
    // 6) GRU scan -> out (fp32; overwrites the scratch)
    gru_k<<<16, 512, 0, stream>>>(w_hh, b_hh, gi_ws, (float*)d_out);
}

// Round 14
// 815.389 us; speedup vs baseline: 1.7482x; 1.0239x over previous
//
#include <hip/hip_runtime.h>
#include <hip/hip_bf16.h>

// Problem dims
#define PP 512
#define QQ 64
#define BB 16
#define EE 256
#define HH 256
#define OO 256

typedef _Float16 half2_t __attribute__((ext_vector_type(2)));
typedef _Float16 f16x8 __attribute__((ext_vector_type(8)));
typedef float f32x4 __attribute__((ext_vector_type(4)));

__device__ __forceinline__ float fast_tanh(float x) {
    x = fminf(fmaxf(x, -15.f), 15.f);
    float e = __expf(2.f * x);
    return (e - 1.f) * __frcp_rn(e + 1.f);
}
__device__ __forceinline__ float fast_sigmoid(float x) {
    x = fminf(fmaxf(x, -30.f), 30.f);
    return __frcp_rn(1.f + __expf(-x));
}
__device__ __forceinline__ f16x8 cvt8(const float* __restrict__ p) {
    float4 r0 = *(const float4*)(p);
    float4 r1 = *(const float4*)(p + 4);
    f16x8 t;
    t[0] = (_Float16)r0.x; t[1] = (_Float16)r0.y;
    t[2] = (_Float16)r0.z; t[3] = (_Float16)r0.w;
    t[4] = (_Float16)r1.x; t[5] = (_Float16)r1.y;
    t[6] = (_Float16)r1.z; t[7] = (_Float16)r1.w;
    return t;
}
__device__ __forceinline__ float fdot2f(half2_t a, half2_t b, float c) {
#if defined(__has_builtin)
#if __has_builtin(__builtin_amdgcn_fdot2)
    return __builtin_amdgcn_fdot2(a, b, c, false);
#else
    return (float)a[0] * (float)b[0] + (float)a[1] * (float)b[1] + c;
#endif
#else
    return (float)a[0] * (float)b[0] + (float)a[1] * (float)b[1] + c;
#endif
}

// LDS-only barrier: orders ds_write -> barrier -> ds_read WITHOUT the
// vmcnt(0)/expcnt(0) drain __syncthreads() emits.
__device__ __forceinline__ void block_sync_lds() {
    __builtin_amdgcn_sched_barrier(0);
    asm volatile("s_waitcnt lgkmcnt(0)" ::: "memory");
    __builtin_amdgcn_s_barrier();
    __builtin_amdgcn_sched_barrier(0);
}

// ---------------------------------------------------------------------------
// One-shot fp32->f16 pre-conversion into d_out scratch (d_out is only
// written by the FINAL gru kernel). f16-element layout in dst:
//   [0,      65536)   Wuq      (256x256)
//   [65536, 131072)   Wup      (256x256)
//   [131072,262144)   Wg2 = Wg rows [256,512)  (256x512)
//   [262144,458752)   w_ih     (768x256)
//   [458752,720896)   question (1024x256 = 262144 elems)
//   [720896,2818048)  passage  (8192x256 = 2097152 elems)
// Total 5.38 MiB < 8 MiB d_out.
// ---------------------------------------------------------------------------
__global__ __launch_bounds__(256) void conv_k(
    const float* __restrict__ Wuq, const float* __restrict__ Wup,
    const float* __restrict__ Wg2, const float* __restrict__ w_ih,
    const float* __restrict__ question, const float* __restrict__ passage,
    _Float16* __restrict__ dst)
{
    const long i = ((long)blockIdx.x * 256 + threadIdx.x) * 8;
    const float* src;
    long off;
    if (i < 65536)       { src = Wuq;      off = i; }
    else if (i < 131072) { src = Wup;      off = i - 65536; }
    else if (i < 262144) { src = Wg2;      off = i - 131072; }
    else if (i < 458752) { src = w_ih;     off = i - 262144; }
    else if (i < 720896) { src = question; off = i - 458752; }
    else                 { src = passage;  off = i - 720896; }
    *(f16x8*)(dst + i) = cvt8(src + off);
}

// ---------------------------------------------------------------------------
// MFMA GEMM body, register-resident f16 B (pre-converted by conv_k).
// MT m-tiles per wave: BM = 64*MT. Wave w owns rows
// [bm*64*MT + (w*MT+mt)*16, +16) for mt in [0,MT). MT=2 halves the number
// of bm blocks -> halves per-GEMM B-staging traffic (the B-strip is
// re-staged once per bm-block) and doubles MFMA work per staging epoch.
// Register check @MT=2: bf 128 + acc <=32 + A-frags 8 ~= 170 <= 256 budget
// (bf/acc AGPR-resident; MFMA reads them in place -- established pattern).
// AMODE: 3 = A f16 (row stride KK)
//        2 = concat (KK=512): k<256 -> Ah2 (stride 256), k>=256 -> Ah
// EPI:   0 none | 1 +bias[n] | 2 sigmoid(acc)*gateC[m*256+n]
// Fragment mappings hardware-verified by the v6 GRU kernel.
// ---------------------------------------------------------------------------
template <int AMODE, int EPI, int BN, int KK, int MT>
__device__ __forceinline__ void gemm_body(
    const _Float16* __restrict__ Ah,
    const _Float16* __restrict__ Ah2,
    const _Float16* __restrict__ Bh,
    const float* __restrict__ bias,
    const _Float16* __restrict__ gateC,
    _Float16* __restrict__ Cout, int N, int bm, int bn, int tid)
{
    constexpr int NT = BN / 16;   // n-tiles per block
    constexpr int KS = KK / 32;   // k-steps
    const int w = tid >> 6;
    const int lane = tid & 63;
    const int ln = lane & 15;     // fragment n / m index
    const int lk = lane >> 4;     // fragment k-group

    f16x8 bf[NT][KS];
#pragma unroll
    for (int c = 0; c < NT; c++) {
        const _Float16* wp = Bh + (long)(bn * BN + c * 16 + ln) * KK + 8 * lk;
#pragma unroll
        for (int kk = 0; kk < KS; kk++)
            bf[c][kk] = *(const f16x8*)(wp + kk * 32);
    }

    f32x4 acc[MT][NT];
#pragma unroll
    for (int mt = 0; mt < MT; mt++)
#pragma unroll
        for (int c = 0; c < NT; c++) acc[mt][c] = (f32x4){0.f, 0.f, 0.f, 0.f};

#pragma unroll
    for (int kk = 0; kk < KS; kk++) {
#pragma unroll
        for (int mt = 0; mt < MT; mt++) {
            const long arow = (long)bm * 64 * MT + (w * MT + mt) * 16 + ln;
            f16x8 a;
            if (AMODE == 3) {
                a = *(const f16x8*)(Ah + arow * KK + kk * 32 + 8 * lk);
            } else {  // AMODE == 2
                if (kk < KS / 2)
                    a = *(const f16x8*)(Ah2 + arow * 256 + kk * 32 + 8 * lk);
                else
                    a = *(const f16x8*)(Ah + arow * 256 + (kk - KS / 2) * 32 + 8 * lk);
            }
#pragma unroll
            for (int c = 0; c < NT; c++)
                acc[mt][c] = __builtin_amdgcn_mfma_f32_16x16x32_f16(
                    a, bf[c][kk], acc[mt][c], 0, 0, 0);
        }
    }

#pragma unroll
    for (int mt = 0; mt < MT; mt++)
#pragma unroll
        for (int c = 0; c < NT; c++) {
            const int n = bn * BN + c * 16 + ln;
            const float bi = (EPI == 1) ? bias[n] : 0.f;
#pragma unroll
            for (int i = 0; i < 4; i++) {
                const long m = (long)bm * 64 * MT + (w * MT + mt) * 16 + lk * 4 + i;
                float v = acc[mt][c][i];
                if (EPI == 1) v += bi;
                if (EPI == 2) v = fast_sigmoid(v) * (float)gateC[m * 256 + n];
                Cout[m * (long)N + n] = (_Float16)v;
            }
        }
}

template <int AMODE, int EPI, int BN, int KK, int MT>
__global__ __launch_bounds__(256)
__attribute__((amdgpu_waves_per_eu(2, 2)))
void gemm_mfma(
    const _Float16* __restrict__ Ah,
    const _Float16* __restrict__ Ah2,
    const _Float16* __restrict__ Bh,
    const float* __restrict__ bias,
    const _Float16* __restrict__ gateC,
    _Float16* __restrict__ Cout, int N)
{
    gemm_body<AMODE, EPI, BN, KK, MT>(Ah, Ah2, Bh, bias, gateC, Cout, N,
                                      blockIdx.x, blockIdx.y, threadIdx.x);
}

// Steps 1+2 merged: bm<8 -> Wq GEMM (question_h @ Wuq^T, M=1024 = 8x128),
// else -> Wp GEMM (passage_h @ Wup^T, M=8192 = 64x128). BM=128 (MT=2).
__global__ __launch_bounds__(256)
__attribute__((amdgpu_waves_per_eu(2, 2)))
void gemm12_k(
    const _Float16* __restrict__ qh, const _Float16* __restrict__ ph,
    const _Float16* __restrict__ wuq, const _Float16* __restrict__ wup,
    _Float16* __restrict__ Wq, _Float16* __restrict__ Wp)
{
    if (blockIdx.x < 8)
        gemm_body<3, 0, 64, 256, 2>(qh, nullptr, wuq, nullptr, nullptr, Wq, 256,
                                    blockIdx.x, blockIdx.y, threadIdx.x);
    else
        gemm_body<3, 0, 64, 256, 2>(ph, nullptr, wup, nullptr, nullptr, Wp, 256,
                                    blockIdx.x - 8, blockIdx.y, threadIdx.x);
}

// ---------------------------------------------------------------------------
// Fused attention: per block = one (p,b) pair (m = p*16+b).
// PV reads pre-converted f16 question.
// ---------------------------------------------------------------------------
__global__ __launch_bounds__(256) void attn_k(
    const _Float16* __restrict__ qh,     // (Q*B, E) f16
    const float* __restrict__ vvec,      // (H,) fp32
    const _Float16* __restrict__ Wp,     // (P*B, H) f16
    const _Float16* __restrict__ Wq,     // (Q*B, H) f16
    _Float16* __restrict__ Cc)           // (P*B, E) f16 out
{
    __shared__ float sc[QQ];
    __shared__ float aw[QQ];
    const int tid = threadIdx.x;
    const int blk = blockIdx.x;   // m = p*16 + b
    const int b = blk & 15;
    const int wave = tid >> 6, lane = tid & 63;

    float wp0[4], vv[4];
#pragma unroll
    for (int j = 0; j < 4; j++) {
        wp0[j] = (float)Wp[(long)blk * 256 + lane + 64 * j];
        vv[j] = vvec[lane + 64 * j];
    }
#pragma unroll 2
    for (int qi = 0; qi < 16; qi++) {
        const int q = wave * 16 + qi;
        const _Float16* wqp = Wq + (long)(q * 16 + b) * 256;
        float s = 0.f;
#pragma unroll
        for (int j = 0; j < 4; j++) {
            float x = (float)wqp[lane + 64 * j] + wp0[j];
            s += fast_tanh(x) * vv[j];
        }
#pragma unroll
        for (int off = 32; off; off >>= 1) s += __shfl_xor(s, off, 64);
        if (lane == 0) sc[q] = s;
    }
    __syncthreads();
    if (tid < 64) {
        float s = sc[tid];
        float mx = s;
#pragma unroll
        for (int off = 32; off; off >>= 1) mx = fmaxf(mx, __shfl_xor(mx, off, 64));
        float e = __expf(s - mx);
        float sum = e;
#pragma unroll
        for (int off = 32; off; off >>= 1) sum += __shfl_xor(sum, off, 64);
        aw[tid] = e * __frcp_rn(sum);
    }
    __syncthreads();
    float acc = 0.f;
#pragma unroll 4
    for (int q = 0; q < QQ; q++) {
        acc = fmaf(aw[q], (float)qh[(long)(q * 16 + b) * 256 + tid], acc);
    }
    Cc[(long)blk * 256 + tid] = (_Float16)acc;
}

// ---------------------------------------------------------------------------
// GRU scan, v10 (best measured: 601us, three times). 16 blocks, 512 threads
// (8 waves, 2/SIMD via waves_per_eu(2,2) -> 256 unified regs).
// Design-space record (rounds 0-12): dot2 half-split @2w/SIMD = 601 (this);
// MFMA = 622; hybrid = 771; 1-wave full-row = 1186; fused-epilogue = 860;
// vmcnt-free barriers = neutral. Structural floor: VALU issue 768 cyc/SIMD
// + >=1/3 AGPR tax (384KB f16 weights vs 256KB arch grant/CU) + LDS/barrier
// skeleton ~= 2800 cyc/step; parallelism capped at 16 CUs by B=16.
// ---------------------------------------------------------------------------
__global__ __launch_bounds__(512)
__attribute__((amdgpu_waves_per_eu(2, 2), amdgpu_num_vgpr(256)))
void gru_k(
    const float* __restrict__ whh,    // (768,256) fp32
    const float* __restrict__ bhh,    // (768,) fp32
    const _Float16* __restrict__ gi,  // (P*B, 768) f16 (b_ih folded in)
    float* __restrict__ out)          // (P,B,O) fp32
{
    __shared__ __align__(16) _Float16 hbuf[2][256];   // h broadcast, dbuf
    __shared__ float part[3][256];                    // q=1 partials
    const int tid = threadIdx.x;
    const int q = tid >> 8;       // K-half 0/1
    const int e = tid & 255;
    const int b = blockIdx.x;
    const int koff = q * 128;

    // Weight slices: rows e (r), e+256 (z), e+512 (n), cols [koff, koff+128)
    half2_t wr[64], wz[64], wn[64];
    {
        const float* pr = whh + (long)e * 256 + koff;
        const float* pz = whh + (long)(e + 256) * 256 + koff;
        const float* pn = whh + (long)(e + 512) * 256 + koff;
#pragma unroll
        for (int j = 0; j < 32; j++) {
            float4 a = *(const float4*)(pr + 4 * j);
            float4 c = *(const float4*)(pz + 4 * j);
            float4 d = *(const float4*)(pn + 4 * j);
            half2_t t;
            t[0] = (_Float16)a.x; t[1] = (_Float16)a.y; wr[2 * j] = t;
            t[0] = (_Float16)a.z; t[1] = (_Float16)a.w; wr[2 * j + 1] = t;
            t[0] = (_Float16)c.x; t[1] = (_Float16)c.y; wz[2 * j] = t;
            t[0] = (_Float16)c.z; t[1] = (_Float16)c.w; wz[2 * j + 1] = t;
            t[0] = (_Float16)d.x; t[1] = (_Float16)d.y; wn[2 * j] = t;
            t[0] = (_Float16)d.z; t[1] = (_Float16)d.w; wn[2 * j + 1] = t;
        }
    }
    float b_r = 0.f, b_z = 0.f, b_n = 0.f;
    _Float16 gr = (_Float16)0.f, gz = (_Float16)0.f, gn = (_Float16)0.f;
    const _Float16* gip = gi;
    float* outp = out;
    if (q == 0) {
        b_r = bhh[e];
        b_z = bhh[e + 256];
        b_n = bhh[e + 512];
        hbuf[0][e] = (_Float16)0.f;
        gip = gi + (long)b * 768 + e;
        gr = gip[0]; gz = gip[256]; gn = gip[512];   // step-0 gi
        outp = out + (long)b * 256 + e;
    }
    float h = 0.f;
    __syncthreads();

    int cur = 0;
    for (int t = 0; t < PP; t++) {
        // Prefetch NEXT step's gi. t=511 reads one row past gi -- inside
        // the 16 MiB workspace, value unused.
        _Float16 gr2 = (_Float16)0.f, gz2 = (_Float16)0.f, gn2 = (_Float16)0.f;
        if (q == 0) {
            const _Float16* gq = gip + 16 * 768;
            gr2 = gq[0]; gz2 = gq[256]; gn2 = gq[512];
        }
        // Half-dot over this thread's 128-wide k-slice of the broadcast h.
        const uint4* hp4 = ((const uint4*)hbuf[cur]) + q * 16;
        float ar = 0.f, az = 0.f, an = 0.f;
#pragma unroll
        for (int j = 0; j < 16; j++) {
            uint4 hp = hp4[j];
            half2_t h0 = __builtin_bit_cast(half2_t, hp.x);
            half2_t h1 = __builtin_bit_cast(half2_t, hp.y);
            half2_t h2 = __builtin_bit_cast(half2_t, hp.z);
            half2_t h3 = __builtin_bit_cast(half2_t, hp.w);
            ar = fdot2f(wr[4 * j + 0], h0, ar);
            ar = fdot2f(wr[4 * j + 1], h1, ar);
            ar = fdot2f(wr[4 * j + 2], h2, ar);
            ar = fdot2f(wr[4 * j + 3], h3, ar);
            az = fdot2f(wz[4 * j + 0], h0, az);
            az = fdot2f(wz[4 * j + 1], h1, az);
            az = fdot2f(wz[4 * j + 2], h2, az);
            az = fdot2f(wz[4 * j + 3], h3, az);
            an = fdot2f(wn[4 * j + 0], h0, an);
            an = fdot2f(wn[4 * j + 1], h1, an);
            an = fdot2f(wn[4 * j + 2], h2, an);
            an = fdot2f(wn[4 * j + 3], h3, an);
        }
        if (q) {
            part[0][e] = ar;
            part[1][e] = az;
            part[2][e] = an;
        }
        block_sync_lds();
        if (q == 0) {
            float ghr = ar + part[0][e] + b_r;
            float ghz = az + part[1][e] + b_z;
            float ghn = an + part[2][e] + b_n;
            float r = fast_sigmoid((float)gr + ghr);
            float z = fast_sigmoid((float)gz + ghz);
            float n = fast_tanh(fmaf(r, ghn, (float)gn));
            h = (1.f - z) * n + z * h;
            *outp = h;
            hbuf[cur ^ 1][e] = (_Float16)h;
            gr = gr2; gz = gz2; gn = gn2;
            gip += 16 * 768;
            outp += 16 * 256;
        }
        block_sync_lds();
        cur ^= 1;
    }
}

// ---------------------------------------------------------------------------
extern "C" void kernel_launch(void* const* d_in, const int* in_sizes, int n_in,
                              void* d_out, int out_size, void* d_ws, size_t ws_size,
                              hipStream_t stream)
{
    const float* passage  = (const float*)d_in[0];   // (512,16,256) fp32
    const float* question = (const float*)d_in[1];   // (64,16,256) fp32
    const float* Wuq      = (const float*)d_in[2];   // (256,256) fp32
    const float* Wup      = (const float*)d_in[3];   // (256,256) fp32
    const float* vvec     = (const float*)d_in[4];   // (1,256) fp32
    const float* Wg       = (const float*)d_in[5];   // (512,512) fp32
    const float* w_ih     = (const float*)d_in[6];   // (768,256) fp32
    const float* w_hh     = (const float*)d_in[7];   // (768,256) fp32
    const float* b_ih     = (const float*)d_in[8];   // (768,) fp32
    const float* b_hh     = (const float*)d_in[9];   // (768,) fp32

    // Workspace layout (all fp16) — total footprint exactly 16 MiB.
    //   [0,      12.0MiB) : gi (8192x768)  — written LAST; overlaps Wq/Wp/c.
    //       [0,     0.5MiB) : Wq (1024x256)   dead after attn
    //       [0.5,   4.5MiB) : Wp (8192x256)   dead after attn
    //       [4.5,   8.5MiB) : c  (8192x256)   dead after gate GEMM
    //   [12MiB, 16MiB)     : cg (8192x256)    alive until gi GEMM done
    // d_out (8 MiB fp32 out) doubles as f16 scratch for pre-converted
    // weights + question + passage until gru_k (the only writer of out).
    char* ws = (char*)d_ws;
    _Float16* gi_ws = (_Float16*)(ws);
    _Float16* Wq_ws = (_Float16*)(ws);
    _Float16* Wp_ws = (_Float16*)(ws + (512u << 10));
    _Float16* c_ws  = (_Float16*)(ws + (4608u << 10));
    _Float16* cg_ws = (_Float16*)(ws + (12288u << 10));

    _Float16* wh     = (_Float16*)d_out;      // f16 scratch
    _Float16* wuq_h  = wh;                    // 256x256
    _Float16* wup_h  = wh + 65536;            // 256x256
    _Float16* wg2_h  = wh + 131072;           // 256x512
    _Float16* wih_h  = wh + 262144;           // 768x256
    _Float16* ques_h = wh + 458752;           // 1024x256 (262144 elems)
    _Float16* pass_h = wh + 720896;           // 8192x256 (2097152 elems)

    // 0) one-shot fp32->f16 conversion into d_out scratch
    //    total 2,818,048 f16 elems / (256 thr * 8) = 1376 blocks exactly
    conv_k<<<1376, 256, 0, stream>>>(Wuq, Wup, Wg + 256 * 512, w_ih,
                                     question, passage, wh);
    // 1+2) Wq = question @ Wuq^T (1024x256) and Wp = passage @ Wup^T
    //      (8192x256), merged; BM=128 (MT=2) halves B-restaging
    gemm12_k<<<dim3(72, 4), 256, 0, stream>>>(ques_h, pass_h, wuq_h, wup_h,
                                              Wq_ws, Wp_ws);
    // 3) attention -> c (8192 x 256)
    attn_k<<<8192, 256, 0, stream>>>(ques_h, vvec, Wp_ws, Wq_ws, c_ws);
    // 4) cg = sigmoid([passage,c] @ Wg[256:512]^T) * c   (8192x256, K=512)
    gemm_mfma<2, 2, 32, 512, 2><<<dim3(64, 8), 256, 0, stream>>>(
        c_ws, pass_h, wg2_h, nullptr, c_ws, cg_ws, 256);
    // 5) gi = cg @ w_ih^T + b_ih   (8192 x 768, K=256)
    gemm_mfma<3, 1, 64, 256, 2><<<dim3(64, 12), 256, 0, stream>>>(
        cg_ws, nullptr, wih_h, b_ih, nullptr, gi_ws, 768);
    // 6) GRU scan -> out (fp32; overwrites the scratch)
    gru_k<<<16, 512, 0, stream>>>(w_hh, b_hh, gi_ws, (float*)d_out);
}